// Round 2
// baseline (275.254 us; speedup 1.0000x reference)
//
#include <hip/hip_runtime.h>
#include <cmath>

// Problem constants: (N,C,H,W) = (16,3,512,512), fp32
#define PLANE (512*512)          // 262144
#define NPLANES 48               // N*C
#define NEL (48*PLANE)           // 12582912

struct Taps { float k[9]; };

// ---------------------------------------------------------------------------
// Kernel 1: fused log(x+1e-6) + W-blur + H-blur, 64x64 output tiles, halo 4.
// grid (8, 8, 96): x=tile_w, y=tile_h, z=plane (0..47 image E, 48..95 image G)
// Phase 2 uses sliding-window float4 LDS reads (stride-72 rows keep banks
// staggered); phase 3 reuses 12 row values for 4 outputs, lanes span cols
// (banks = c mod 32 -> 2 lanes/bank, free).
// ---------------------------------------------------------------------------
__global__ __launch_bounds__(256)
void k_blur_hw(const float* __restrict__ inE, const float* __restrict__ inG,
               float* __restrict__ outE, float* __restrict__ outG, Taps tp)
{
    __shared__ float raw[72*72];   // log values, rows h0-4..h0+67, cols w0-4..w0+67
    __shared__ float wb[72*64];    // W-blurred, 72 rows x 64 output cols

    const int tid = threadIdx.x;
    const int w0 = blockIdx.x * 64;
    const int h0 = blockIdx.y * 64;
    const int z  = blockIdx.z;

    const float* src;
    float* dst;
    if (z < NPLANES) { src = inE + z * PLANE;              dst = outE + z * PLANE; }
    else             { src = inG + (z - NPLANES) * PLANE;  dst = outG + (z - NPLANES) * PLANE; }

    // Phase 1: load 72x72 with symmetric fold at 0/511, fast log once/elem
    for (int j = tid; j < 72*72; j += 256) {
        int r = j / 72;
        int c = j - r * 72;
        int h = h0 + r - 4; h = (h < 0) ? (-1 - h) : ((h > 511) ? (1023 - h) : h);
        int w = w0 + c - 4; w = (w < 0) ? (-1 - w) : ((w > 511) ? (1023 - w) : w);
        raw[j] = __logf(src[h * 512 + w] + 1e-6f);
    }
    __syncthreads();

    // Phase 2: blur along W -> wb[72][64]. 4 outputs/task via sliding window.
    // 72*16 = 1152 tasks.
    for (int j = tid; j < 72*16; j += 256) {
        int r  = j >> 4;
        int cg = (j & 15) << 2;
        const float4* rp = (const float4*)&raw[r * 72 + cg];  // 16B aligned
        float x[12];
        ((float4*)x)[0] = rp[0];
        ((float4*)x)[1] = rp[1];
        ((float4*)x)[2] = rp[2];
        float4 o = make_float4(0.f, 0.f, 0.f, 0.f);
#pragma unroll
        for (int t = 0; t < 9; ++t) {
            float kt = tp.k[t];
            o.x += kt * x[t];
            o.y += kt * x[t + 1];
            o.z += kt * x[t + 2];
            o.w += kt * x[t + 3];
        }
        *(float4*)&wb[r * 64 + cg] = o;
    }
    __syncthreads();

    // Phase 3: blur along H; each task = 1 col x 4 rows (12 reads -> 4 outputs).
    // 64 cols x 16 row-groups = 1024 tasks; lanes span cols -> conflict-free.
    for (int j = tid; j < 1024; j += 256) {
        int c  = j & 63;
        int rb = (j >> 6) << 2;
        float x[12];
#pragma unroll
        for (int t = 0; t < 12; ++t) x[t] = wb[(rb + t) * 64 + c];
#pragma unroll
        for (int i = 0; i < 4; ++i) {
            float s = 0.f;
#pragma unroll
            for (int t = 0; t < 9; ++t) s += tp.k[t] * x[i + t];
            dst[(h0 + rb + i) * 512 + (w0 + c)] = s;
        }
    }
}

// ---------------------------------------------------------------------------
// Kernel 2: C-blur + N-blur + loss terms, fused. One thread per (h,w).
// log eliminated algebraically: R = (I+1e-6)*exp(-S), L = exp(S).
// Live registers ~= tce[48]+tcg[48]+small -> aim for 4 blocks/CU.
// grid (1024), block (256)
// ---------------------------------------------------------------------------
__global__ __launch_bounds__(256, 4)
void k_cn_loss(const float* __restrict__ Ae, const float* __restrict__ Ag,
               const float* __restrict__ Ie, const float* __restrict__ Ig,
               float* __restrict__ part, Taps tp)
{
    const int hw = blockIdx.x * 256 + threadIdx.x;

    // symmetric fold of c-4+t for size-3 axis (period-6 mirror), c = 0,1,2
    const int F3[3][9] = {
        {2,2,1,0,0,1,2,2,1},
        {2,1,0,0,1,2,2,1,0},
        {1,0,0,1,2,2,1,0,0}
    };

    float tce[48];  // C-blurred smoothed-log(E)
    float tcg[48];  // C-blurred smoothed-log(G)

    // C-blur needs only the 3 channel values of each n at a time.
#pragma unroll
    for (int n = 0; n < 16; ++n) {
        float v0 = Ae[(n * 3 + 0) * PLANE + hw];
        float v1 = Ae[(n * 3 + 1) * PLANE + hw];
        float v2 = Ae[(n * 3 + 2) * PLANE + hw];
        float v[3] = {v0, v1, v2};
#pragma unroll
        for (int c = 0; c < 3; ++c) {
            float s = 0.f;
#pragma unroll
            for (int t = 0; t < 9; ++t) s += tp.k[t] * v[F3[c][t]];
            tce[n * 3 + c] = s;
        }
    }
#pragma unroll
    for (int n = 0; n < 16; ++n) {
        float v0 = Ag[(n * 3 + 0) * PLANE + hw];
        float v1 = Ag[(n * 3 + 1) * PLANE + hw];
        float v2 = Ag[(n * 3 + 2) * PLANE + hw];
        float v[3] = {v0, v1, v2};
#pragma unroll
        for (int c = 0; c < 3; ++c) {
            float s = 0.f;
#pragma unroll
            for (int t = 0; t < 9; ++t) s += tp.k[t] * v[F3[c][t]];
            tcg[n * 3 + c] = s;
        }
    }

    // N-blur inline, then loss terms (no logs needed: R=(I+eps)*exp(-S))
    float acc = 0.f;
#pragma unroll
    for (int n = 0; n < 16; ++n) {
#pragma unroll
        for (int c = 0; c < 3; ++c) {
            float se = 0.f, sg = 0.f;
#pragma unroll
            for (int t = 0; t < 9; ++t) {
                int m = n - 4 + t;
                m = (m < 0) ? (-1 - m) : ((m > 15) ? (31 - m) : m);
                se += tp.k[t] * tce[m * 3 + c];
                sg += tp.k[t] * tcg[m * 3 + c];
            }
            const int j = n * 3 + c;
            float ie = Ie[j * PLANE + hw] + 1e-6f;
            float ig = Ig[j * PLANE + hw] + 1e-6f;
            float Re = ie * __expf(-se);
            float Rg = ig * __expf(-sg);
            float Le = __expf(se);
            float Lg = __expf(sg);
            float dr = Re - Rg;
            float dl = Le - Lg;
            acc += dr * dr + dl * dl;
        }
    }

    __shared__ float red[256];
    red[threadIdx.x] = acc;
    __syncthreads();
#pragma unroll
    for (int s = 128; s > 0; s >>= 1) {
        if (threadIdx.x < s) red[threadIdx.x] += red[threadIdx.x + s];
        __syncthreads();
    }
    if (threadIdx.x == 0) part[blockIdx.x] = red[0];
}

// ---------------------------------------------------------------------------
// Kernel 3: reduce 1024 partials, scale by 1/NEL
// ---------------------------------------------------------------------------
__global__ __launch_bounds__(256)
void k_final(const float* __restrict__ part, float* __restrict__ out)
{
    __shared__ float red[256];
    float a = 0.f;
    for (int i = threadIdx.x; i < 1024; i += 256) a += part[i];
    red[threadIdx.x] = a;
    __syncthreads();
#pragma unroll
    for (int s = 128; s > 0; s >>= 1) {
        if (threadIdx.x < s) red[threadIdx.x] += red[threadIdx.x + s];
        __syncthreads();
    }
    if (threadIdx.x == 0) out[0] = red[0] * (1.0f / (float)NEL);
}

extern "C" void kernel_launch(void* const* d_in, const int* in_sizes, int n_in,
                              void* d_out, int out_size, void* d_ws, size_t ws_size,
                              hipStream_t stream) {
    const float* Ie = (const float*)d_in[0];
    const float* Ig = (const float*)d_in[1];

    // Gaussian taps: sigma=1, radius=int(4*1+0.5)=4, double-precision normalize
    // then cast to float -- matches the reference kernel construction.
    Taps tp;
    {
        double kk[9], s = 0.0;
        for (int i = 0; i < 9; ++i) { double x = (double)(i - 4); kk[i] = exp(-0.5 * x * x); s += kk[i]; }
        for (int i = 0; i < 9; ++i) tp.k[i] = (float)(kk[i] / s);
    }

    float* Ae   = (float*)d_ws;          // HW-blurred log(Ie), 48 MB
    float* Ag   = Ae + NEL;              // HW-blurred log(Ig), 48 MB
    float* part = Ag + NEL;              // 1024 block partials

    dim3 g1(8, 8, 96);
    k_blur_hw<<<g1, 256, 0, stream>>>(Ie, Ig, Ae, Ag, tp);
    k_cn_loss<<<1024, 256, 0, stream>>>(Ae, Ag, Ie, Ig, part, tp);
    k_final<<<1, 256, 0, stream>>>(part, (float*)d_out);
}

// Round 3
// 190.131 us; speedup vs baseline: 1.4477x; 1.4477x over previous
//
#include <hip/hip_runtime.h>
#include <cmath>

// Problem constants: (N,C,H,W) = (16,3,512,512), fp32
#define PLANE (512*512)          // 262144
#define NPLANES 48               // N*C
#define NEL (48*PLANE)           // 12582912

struct Taps  { float k[9]; };
struct CMat  { float w[3][3]; };   // C-axis 9-tap blur collapsed to 3x3 matrix

// ---------------------------------------------------------------------------
// Kernel 1: fused log(x+1e-6) + W-blur + H-blur, 64x64 output tiles, halo 4.
// grid (8, 8, 96): x=tile_w, y=tile_h, z=plane (0..47 image E, 48..95 image G)
// ---------------------------------------------------------------------------
__global__ __launch_bounds__(256)
void k_blur_hw(const float* __restrict__ inE, const float* __restrict__ inG,
               float* __restrict__ outE, float* __restrict__ outG, Taps tp)
{
    __shared__ float raw[72*72];   // log values, rows h0-4..h0+67, cols w0-4..w0+67
    __shared__ float wb[72*64];    // W-blurred, 72 rows x 64 output cols

    const int tid = threadIdx.x;
    const int w0 = blockIdx.x * 64;
    const int h0 = blockIdx.y * 64;
    const int z  = blockIdx.z;

    const float* src;
    float* dst;
    if (z < NPLANES) { src = inE + z * PLANE;              dst = outE + z * PLANE; }
    else             { src = inG + (z - NPLANES) * PLANE;  dst = outG + (z - NPLANES) * PLANE; }

    // Phase 1: load 72x72 with symmetric fold at 0/511, fast log once/elem
    for (int j = tid; j < 72*72; j += 256) {
        int r = j / 72;
        int c = j - r * 72;
        int h = h0 + r - 4; h = (h < 0) ? (-1 - h) : ((h > 511) ? (1023 - h) : h);
        int w = w0 + c - 4; w = (w < 0) ? (-1 - w) : ((w > 511) ? (1023 - w) : w);
        raw[j] = __logf(src[h * 512 + w] + 1e-6f);
    }
    __syncthreads();

    // Phase 2: blur along W -> wb[72][64]. 4 outputs/task via sliding window.
    for (int j = tid; j < 72*16; j += 256) {
        int r  = j >> 4;
        int cg = (j & 15) << 2;
        const float4* rp = (const float4*)&raw[r * 72 + cg];  // 16B aligned
        float x[12];
        ((float4*)x)[0] = rp[0];
        ((float4*)x)[1] = rp[1];
        ((float4*)x)[2] = rp[2];
        float4 o = make_float4(0.f, 0.f, 0.f, 0.f);
#pragma unroll
        for (int t = 0; t < 9; ++t) {
            float kt = tp.k[t];
            o.x += kt * x[t];
            o.y += kt * x[t + 1];
            o.z += kt * x[t + 2];
            o.w += kt * x[t + 3];
        }
        *(float4*)&wb[r * 64 + cg] = o;
    }
    __syncthreads();

    // Phase 3: blur along H; each task = 1 col x 4 rows (12 reads -> 4 outputs).
    for (int j = tid; j < 1024; j += 256) {
        int c  = j & 63;
        int rb = (j >> 6) << 2;
        float x[12];
#pragma unroll
        for (int t = 0; t < 12; ++t) x[t] = wb[(rb + t) * 64 + c];
#pragma unroll
        for (int i = 0; i < 4; ++i) {
            float s = 0.f;
#pragma unroll
            for (int t = 0; t < 9; ++t) s += tp.k[t] * x[i + t];
            dst[(h0 + rb + i) * 512 + (w0 + c)] = s;
        }
    }
}

// ---------------------------------------------------------------------------
// Kernel 2: C-blur + N-blur + loss, fused, register-light.
//  - C-blur: 3x3 matrix W3 (host-precomputed, lives in SGPRs).
//  - N-blur: 9-entry sliding ring (all folded indices for output n lie in
//    [max(0,n-4), min(15,n+4)]), fully unrolled -> compile-time slots.
//  Live regs ~= ring 54 + temps. NO VGPR cap (R2's 64-cap caused 160MB spill).
// grid (1024), block (256); one thread per (h,w).
// ---------------------------------------------------------------------------
__global__ __launch_bounds__(256)
void k_cn_loss(const float* __restrict__ Ae, const float* __restrict__ Ag,
               const float* __restrict__ Ie, const float* __restrict__ Ig,
               float* __restrict__ part, Taps tp, CMat cm)
{
    const int hw = blockIdx.x * 256 + threadIdx.x;

    float re[9][3];   // ring of C-blurred smoothed-log(E), slot = m % 9
    float rg[9][3];   // ditto for G

#define LOADCB(m, ring, A)                                                    \
    {                                                                         \
        float v0 = A[((m) * 3 + 0) * PLANE + hw];                             \
        float v1 = A[((m) * 3 + 1) * PLANE + hw];                             \
        float v2 = A[((m) * 3 + 2) * PLANE + hw];                             \
        ring[(m) % 9][0] = cm.w[0][0] * v0 + cm.w[0][1] * v1 + cm.w[0][2] * v2; \
        ring[(m) % 9][1] = cm.w[1][0] * v0 + cm.w[1][1] * v1 + cm.w[1][2] * v2; \
        ring[(m) % 9][2] = cm.w[2][0] * v0 + cm.w[2][1] * v1 + cm.w[2][2] * v2; \
    }

#pragma unroll
    for (int m = 0; m < 4; ++m) { LOADCB(m, re, Ae); LOADCB(m, rg, Ag); }

    float acc = 0.f;
#pragma unroll
    for (int n = 0; n < 16; ++n) {
        const int mnew = n + 4;
        if (mnew < 16) { LOADCB(mnew, re, Ae); LOADCB(mnew, rg, Ag); }
#pragma unroll
        for (int c = 0; c < 3; ++c) {
            float se = 0.f, sg = 0.f;
#pragma unroll
            for (int t = 0; t < 9; ++t) {
                int m = n - 4 + t;
                m = (m < 0) ? (-1 - m) : ((m > 15) ? (31 - m) : m);  // compile-time
                se += tp.k[t] * re[m % 9][c];
                sg += tp.k[t] * rg[m % 9][c];
            }
            const int j = n * 3 + c;
            float ie = Ie[j * PLANE + hw] + 1e-6f;
            float ig = Ig[j * PLANE + hw] + 1e-6f;
            float ee = __expf(-se);                  // 1/Le
            float eg = __expf(-sg);
            float Re = ie * ee;
            float Rg = ig * eg;
            float Le = __builtin_amdgcn_rcpf(ee);    // exp(se), ~1e-6 rel err
            float Lg = __builtin_amdgcn_rcpf(eg);
            float dr = Re - Rg;
            float dl = Le - Lg;
            acc += dr * dr + dl * dl;
        }
    }
#undef LOADCB

    __shared__ float red[256];
    red[threadIdx.x] = acc;
    __syncthreads();
#pragma unroll
    for (int s = 128; s > 0; s >>= 1) {
        if (threadIdx.x < s) red[threadIdx.x] += red[threadIdx.x + s];
        __syncthreads();
    }
    if (threadIdx.x == 0) part[blockIdx.x] = red[0];
}

// ---------------------------------------------------------------------------
// Kernel 3: reduce 1024 partials, scale by 1/NEL
// ---------------------------------------------------------------------------
__global__ __launch_bounds__(256)
void k_final(const float* __restrict__ part, float* __restrict__ out)
{
    __shared__ float red[256];
    float a = 0.f;
    for (int i = threadIdx.x; i < 1024; i += 256) a += part[i];
    red[threadIdx.x] = a;
    __syncthreads();
#pragma unroll
    for (int s = 128; s > 0; s >>= 1) {
        if (threadIdx.x < s) red[threadIdx.x] += red[threadIdx.x + s];
        __syncthreads();
    }
    if (threadIdx.x == 0) out[0] = red[0] * (1.0f / (float)NEL);
}

extern "C" void kernel_launch(void* const* d_in, const int* in_sizes, int n_in,
                              void* d_out, int out_size, void* d_ws, size_t ws_size,
                              hipStream_t stream) {
    const float* Ie = (const float*)d_in[0];
    const float* Ig = (const float*)d_in[1];

    // Gaussian taps: sigma=1, radius=int(4*1+0.5)=4, double-precision normalize
    // then cast to float -- matches the reference kernel construction.
    Taps tp;
    {
        double kk[9], s = 0.0;
        for (int i = 0; i < 9; ++i) { double x = (double)(i - 4); kk[i] = exp(-0.5 * x * x); s += kk[i]; }
        for (int i = 0; i < 9; ++i) tp.k[i] = (float)(kk[i] / s);
    }

    // C-axis (size 3) 9-tap symmetric blur collapsed to a 3x3 matrix:
    // W3[c][c'] = sum over taps t where symmetric-fold(c-4+t) == c'
    CMat cm;
    {
        for (int c = 0; c < 3; ++c) {
            cm.w[c][0] = cm.w[c][1] = cm.w[c][2] = 0.f;
            for (int t = 0; t < 9; ++t) {
                int m = c - 4 + t;
                int mm = ((m % 6) + 6) % 6;          // symmetric reflect, period 6
                if (mm > 2) mm = 5 - mm;
                cm.w[c][mm] += tp.k[t];
            }
        }
    }

    float* Ae   = (float*)d_ws;          // HW-blurred log(Ie), 48 MB
    float* Ag   = Ae + NEL;              // HW-blurred log(Ig), 48 MB
    float* part = Ag + NEL;              // 1024 block partials

    dim3 g1(8, 8, 96);
    k_blur_hw<<<g1, 256, 0, stream>>>(Ie, Ig, Ae, Ag, tp);
    k_cn_loss<<<1024, 256, 0, stream>>>(Ae, Ag, Ie, Ig, part, tp, cm);
    k_final<<<1, 256, 0, stream>>>(part, (float*)d_out);
}

// Round 4
// 181.690 us; speedup vs baseline: 1.5150x; 1.0465x over previous
//
#include <hip/hip_runtime.h>
#include <cmath>

// Problem constants: (N,C,H,W) = (16,3,512,512), fp32
#define PLANE (512*512)          // 262144
#define NPLANES 48               // N*C
#define NEL (48*PLANE)           // 12582912

struct Taps { float k[9]; };
struct CMat { float w[3][3]; };   // C-axis 9-tap blur collapsed to 3x3 matrix

// ws layout for the HW-blurred logs (TILED for k_cn_loss locality):
//   index(p, h, w) = ((h*8 + (w>>6))*96 + p)*64 + (w&63)
//   p in [0,48) = image E planes, [48,96) = image G planes.
// k_cn_loss then reads 96 consecutive 256B rows per wave (one 24KB stream)
// instead of 96 streams strided by exactly 1MB (pow2 channel aliasing).

// ---------------------------------------------------------------------------
// Kernel 1: fused log + W-blur + H-blur. One WAVE (block=64) per 32-row strip
// of one plane, full 512-col width. No LDS: W-halo via shuffles, H-blur via a
// 10-row register ring with compile-time slots. Row prefetch depth 1.
// grid (16 rowgroups, 96 planes), block 64.
// ---------------------------------------------------------------------------
__global__ __launch_bounds__(64)
void k_blur_hw(const float* __restrict__ inE, const float* __restrict__ inG,
               float* __restrict__ ws, Taps tp)
{
    const int l  = threadIdx.x;          // lane 0..63, owns cols 8l..8l+7
    const int r0 = blockIdx.x * 32;      // first output row of this strip
    const int z  = blockIdx.y;           // plane 0..95

    const float* src = (z < NPLANES) ? (inE + z * PLANE)
                                     : (inG + (z - NPLANES) * PLANE);

    const bool is0  = (l == 0);
    const bool is63 = (l == 63);
    const int  vout = (l >> 3) * 6144 + (l & 7) * 8;  // lane offset in tiled ws

    float ring[10][8];                   // W-blurred rows, slot = row_idx % 10

    // prefetch input row j=0 (plane row r0-4, folded)
    int rp0 = r0 - 4;
    rp0 = (rp0 < 0) ? (-1 - rp0) : ((rp0 > 511) ? (1023 - rp0) : rp0);
    float4 a = *(const float4*)(src + rp0 * 512 + l * 8);
    float4 b = *(const float4*)(src + rp0 * 512 + l * 8 + 4);

    for (int jb = 0; jb < 40; jb += 10) {
#pragma unroll
        for (int u = 0; u < 10; ++u) {
            const int j = jb + u;        // input row index 0..39 (plane r0-4+j)

            // prefetch row j+1 (always; folded addr stays in-bounds)
            int rn = r0 - 4 + j + 1;
            rn = (rn < 0) ? (-1 - rn) : ((rn > 511) ? (1023 - rn) : rn);
            const float* nrp = src + rn * 512 + l * 8;
            float4 na = *(const float4*)nrp;
            float4 nb = *(const float4*)(nrp + 4);

            // log of own 8 cols
            float win[16];
            win[4]  = __logf(a.x + 1e-6f);
            win[5]  = __logf(a.y + 1e-6f);
            win[6]  = __logf(a.z + 1e-6f);
            win[7]  = __logf(a.w + 1e-6f);
            win[8]  = __logf(b.x + 1e-6f);
            win[9]  = __logf(b.y + 1e-6f);
            win[10] = __logf(b.z + 1e-6f);
            win[11] = __logf(b.w + 1e-6f);

            // halo: left = prev lane's high float4, right = next lane's low.
            // Image-edge mirror = reverse of own values (lanes 0 / 63).
            float s;
            s = __shfl_up(win[8], 1);   win[0]  = is0  ? win[7]  : s;
            s = __shfl_up(win[9], 1);   win[1]  = is0  ? win[6]  : s;
            s = __shfl_up(win[10], 1);  win[2]  = is0  ? win[5]  : s;
            s = __shfl_up(win[11], 1);  win[3]  = is0  ? win[4]  : s;
            s = __shfl_down(win[4], 1); win[12] = is63 ? win[11] : s;
            s = __shfl_down(win[5], 1); win[13] = is63 ? win[10] : s;
            s = __shfl_down(win[6], 1); win[14] = is63 ? win[9]  : s;
            s = __shfl_down(win[7], 1); win[15] = is63 ? win[8]  : s;

            // W-blur -> ring slot u (compile-time)
#pragma unroll
            for (int i = 0; i < 8; ++i) {
                float o = 0.f;
#pragma unroll
                for (int t = 0; t < 9; ++t) o += tp.k[t] * win[i + t];
                ring[u][i] = o;
            }

            // H-blur + store once 9 rows are live (output plane row r0+j-8)
            if (j >= 8) {
                float acc[8];
#pragma unroll
                for (int i = 0; i < 8; ++i) {
                    float o = 0.f;
#pragma unroll
                    for (int t = 0; t < 9; ++t)
                        o += tp.k[t] * ring[(u + 2 + t) % 10][i];  // slot of row j-8+t
                    acc[i] = o;
                }
                const int ro = r0 + j - 8;
                float* dp = ws + (ro * 768 + z) * 64 + vout;
                *(float4*)dp       = make_float4(acc[0], acc[1], acc[2], acc[3]);
                *(float4*)(dp + 4) = make_float4(acc[4], acc[5], acc[6], acc[7]);
            }
            a = na; b = nb;
        }
    }
}

// ---------------------------------------------------------------------------
// Kernel 2: C-blur + N-blur + loss, register-light (9-slot ring, 3x3 C-matrix).
// Reads the TILED ws (contiguous per wave) + Ie/Ig (fixed input layout).
// grid (1024), block (256); one thread per (h,w).
// ---------------------------------------------------------------------------
__global__ __launch_bounds__(256)
void k_cn_loss(const float* __restrict__ ws, const float* __restrict__ Ie,
               const float* __restrict__ Ig, float* __restrict__ part,
               Taps tp, CMat cm)
{
    const int tid = threadIdx.x;
    const int hw  = blockIdx.x * 256 + tid;
    const float* wbase = ws + (hw >> 6) * (96 * 64) + (hw & 63);
    // E plane q at wbase[q*64], G plane q at wbase[(48+q)*64]

    float re[9][3];   // ring of C-blurred smoothed-log(E), slot = m % 9
    float rg[9][3];

#define LOADCB(m, ring, OFF)                                                   \
    {                                                                          \
        float v0 = wbase[((OFF) + (m) * 3 + 0) * 64];                          \
        float v1 = wbase[((OFF) + (m) * 3 + 1) * 64];                          \
        float v2 = wbase[((OFF) + (m) * 3 + 2) * 64];                          \
        ring[(m) % 9][0] = cm.w[0][0]*v0 + cm.w[0][1]*v1 + cm.w[0][2]*v2;      \
        ring[(m) % 9][1] = cm.w[1][0]*v0 + cm.w[1][1]*v1 + cm.w[1][2]*v2;      \
        ring[(m) % 9][2] = cm.w[2][0]*v0 + cm.w[2][1]*v1 + cm.w[2][2]*v2;      \
    }

#pragma unroll
    for (int m = 0; m < 4; ++m) { LOADCB(m, re, 0); LOADCB(m, rg, 48); }

    float acc = 0.f;
#pragma unroll
    for (int n = 0; n < 16; ++n) {
        const int mnew = n + 4;
        if (mnew < 16) { LOADCB(mnew, re, 0); LOADCB(mnew, rg, 48); }
#pragma unroll
        for (int c = 0; c < 3; ++c) {
            float se = 0.f, sg = 0.f;
#pragma unroll
            for (int t = 0; t < 9; ++t) {
                int m = n - 4 + t;
                m = (m < 0) ? (-1 - m) : ((m > 15) ? (31 - m) : m);  // compile-time
                se += tp.k[t] * re[m % 9][c];
                sg += tp.k[t] * rg[m % 9][c];
            }
            const int j = n * 3 + c;
            float ie = Ie[j * PLANE + hw] + 1e-6f;
            float ig = Ig[j * PLANE + hw] + 1e-6f;
            float ee = __expf(-se);                  // 1/Le
            float eg = __expf(-sg);
            float Re = ie * ee;
            float Rg = ig * eg;
            float Le = __builtin_amdgcn_rcpf(ee);    // exp(se)
            float Lg = __builtin_amdgcn_rcpf(eg);
            float dr = Re - Rg;
            float dl = Le - Lg;
            acc += dr * dr + dl * dl;
        }
    }
#undef LOADCB

    __shared__ float red[256];
    red[tid] = acc;
    __syncthreads();
#pragma unroll
    for (int s = 128; s > 0; s >>= 1) {
        if (tid < s) red[tid] += red[tid + s];
        __syncthreads();
    }
    if (tid == 0) part[blockIdx.x] = red[0];
}

// ---------------------------------------------------------------------------
// Kernel 3: reduce 1024 partials, scale by 1/NEL
// ---------------------------------------------------------------------------
__global__ __launch_bounds__(256)
void k_final(const float* __restrict__ part, float* __restrict__ out)
{
    __shared__ float red[256];
    float a = 0.f;
    for (int i = threadIdx.x; i < 1024; i += 256) a += part[i];
    red[threadIdx.x] = a;
    __syncthreads();
#pragma unroll
    for (int s = 128; s > 0; s >>= 1) {
        if (threadIdx.x < s) red[threadIdx.x] += red[threadIdx.x + s];
        __syncthreads();
    }
    if (threadIdx.x == 0) out[0] = red[0] * (1.0f / (float)NEL);
}

extern "C" void kernel_launch(void* const* d_in, const int* in_sizes, int n_in,
                              void* d_out, int out_size, void* d_ws, size_t ws_size,
                              hipStream_t stream) {
    const float* Ie = (const float*)d_in[0];
    const float* Ig = (const float*)d_in[1];

    // Gaussian taps: sigma=1, radius=int(4*1+0.5)=4, double-precision normalize
    Taps tp;
    {
        double kk[9], s = 0.0;
        for (int i = 0; i < 9; ++i) { double x = (double)(i - 4); kk[i] = exp(-0.5 * x * x); s += kk[i]; }
        for (int i = 0; i < 9; ++i) tp.k[i] = (float)(kk[i] / s);
    }

    // C-axis (size 3) 9-tap symmetric blur collapsed to a 3x3 matrix
    CMat cm;
    {
        for (int c = 0; c < 3; ++c) {
            cm.w[c][0] = cm.w[c][1] = cm.w[c][2] = 0.f;
            for (int t = 0; t < 9; ++t) {
                int m = c - 4 + t;
                int mm = ((m % 6) + 6) % 6;          // symmetric reflect, period 6
                if (mm > 2) mm = 5 - mm;
                cm.w[c][mm] += tp.k[t];
            }
        }
    }

    float* ws   = (float*)d_ws;          // tiled blurred logs, 96 MB (2*NEL floats)
    float* part = ws + 2 * (size_t)NEL;  // 1024 block partials

    dim3 g1(16, 96);
    k_blur_hw<<<g1, 64, 0, stream>>>(Ie, Ig, ws, tp);
    k_cn_loss<<<1024, 256, 0, stream>>>(ws, Ie, Ig, part, tp, cm);
    k_final<<<1, 256, 0, stream>>>(part, (float*)d_out);
}